// Round 1
// baseline (16056.865 us; speedup 1.0000x reference)
//
#include <hip/hip_runtime.h>

#define HDIM  128
#define G3    384
#define RPB   32            // rows per block
#define NTHR  512
#define NSTEP 256
#define NOUT  33
#define BROWS 8192
#define LOGP_ELEMS 69206016LL   // 8192*256*33

// LDS layout (float offsets)
#define H_LD    36          // transposed h: [128][36], float4-aligned rows, conflict-free
#define GA_LD   385
#define PRED_LD 34
#define OFF_H0   0
#define OFF_H1   (128*H_LD)                  // 4608
#define OFF_GA   (2*128*H_LD)                // 9216
#define OFF_GB   (OFF_GA + RPB*GA_LD)        // 21536
#define OFF_PRED (OFF_GB + RPB*GA_LD)        // 33856
#define OFF_ACTS (OFF_PRED + RPB*PRED_LD)    // 34944
#define LDS_FLOATS (OFF_ACTS + RPB)          // 34976
#define LDS_BYTES  (LDS_FLOATS*4)            // 139904 < 160 KiB

__device__ __forceinline__ float sigf(float x) { return 1.0f / (1.0f + __expf(-x)); }
__device__ __forceinline__ float tanh_fast(float x) { return 1.0f - 2.0f / (__expf(2.0f*x) + 1.0f); }

// Precompute gi0 tables: T1[a][g] for dur=1, T0[g] for (act=0, dur=0)
__global__ void prep_kernel(const float* __restrict__ emb, const float* __restrict__ wih0,
                            const float* __restrict__ bih0, float* __restrict__ T1,
                            float* __restrict__ T0) {
    int a = blockIdx.x;          // 0..31
    int g = threadIdx.x;         // 0..383
    const float* e = emb + a * 127;
    const float* w = wih0 + g * HDIM;
    float s = bih0[g];
    for (int k = 0; k < 127; ++k) s += e[k] * w[k];
    T1[a * G3 + g] = s + w[127];           // dur = 1 contribution
    if (a == 0) T0[g] = s;                 // step 0: act=0, dur=0
}

// One GEMV phase: dst[r][g] = src_h[:, r] . W[g, :] + bias[g]
// src_h is transposed LDS [128][H_LD]; each thread: 4 rows (rb) x 6 gates (gblk)
__device__ __forceinline__ void gemm_phase(const float* __restrict__ W,
                                           const float* __restrict__ bias,
                                           const float* __restrict__ srcT,
                                           float* __restrict__ dst,
                                           int rb, int gblk) {
    const int g0 = gblk * 6;
    float acc[4][6];
#pragma unroll
    for (int i = 0; i < 4; ++i)
#pragma unroll
        for (int j = 0; j < 6; ++j) acc[i][j] = 0.0f;

    const float4* __restrict__ h4 = (const float4*)srcT;            // [128][9]
    const float4* __restrict__ w4 = (const float4*)(W + g0 * HDIM); // [6][32]

    for (int k4 = 0; k4 < 32; ++k4) {
        float4 ha = h4[(4*k4 + 0)*9 + rb];
        float4 hb = h4[(4*k4 + 1)*9 + rb];
        float4 hc = h4[(4*k4 + 2)*9 + rb];
        float4 hd = h4[(4*k4 + 3)*9 + rb];
        float A[4] = {ha.x, ha.y, ha.z, ha.w};
        float B[4] = {hb.x, hb.y, hb.z, hb.w};
        float C[4] = {hc.x, hc.y, hc.z, hc.w};
        float D[4] = {hd.x, hd.y, hd.z, hd.w};
#pragma unroll
        for (int j = 0; j < 6; ++j) {
            float4 wv = w4[j*32 + k4];
#pragma unroll
            for (int i = 0; i < 4; ++i) {
                acc[i][j] += A[i]*wv.x + B[i]*wv.y + C[i]*wv.z + D[i]*wv.w;
            }
        }
    }
#pragma unroll
    for (int j = 0; j < 6; ++j) {
        float bj = bias[g0 + j];
#pragma unroll
        for (int i = 0; i < 4; ++i)
            dst[(rb*4 + i)*GA_LD + g0 + j] = acc[i][j] + bj;
    }
}

__launch_bounds__(NTHR)
__global__ void decoder_kernel(const float* __restrict__ hid,
                               const float* __restrict__ T1, const float* __restrict__ T0,
                               const float* __restrict__ whh0, const float* __restrict__ bhh0,
                               const float* __restrict__ wih1, const float* __restrict__ bih1,
                               const float* __restrict__ whh1, const float* __restrict__ bhh1,
                               const float* __restrict__ fcw,  const float* __restrict__ fcb,
                               float* __restrict__ out) {
    extern __shared__ float sm[];
    float* h0s   = sm + OFF_H0;    // [128][H_LD] transposed
    float* h1s   = sm + OFF_H1;
    float* ga    = sm + OFF_GA;    // [32][GA_LD]
    float* gb    = sm + OFF_GB;
    float* preds = sm + OFF_PRED;  // [32][PRED_LD]
    int*   acts  = (int*)(sm + OFF_ACTS);

    const int tid  = threadIdx.x;
    const int row0 = blockIdx.x * RPB;
    float* lp = out;
    float* pp = out + LOGP_ELEMS;

    // init h (transposed into LDS)
    for (int idx = tid; idx < RPB*HDIM; idx += NTHR) {
        int r = idx >> 7, k = idx & 127;
        h0s[k*H_LD + r] = hid[(size_t)(row0 + r)*HDIM + k];
        h1s[k*H_LD + r] = hid[(size_t)BROWS*HDIM + (size_t)(row0 + r)*HDIM + k];
    }
    __syncthreads();

    const int rb   = tid & 7;   // 8 row-blocks of 4
    const int gblk = tid >> 3;  // 64 gate-blocks of 6

    for (int t = 0; t < NSTEP; ++t) {
        // P1: ga = gh0 = h0 . Whh0^T + bhh0
        gemm_phase(whh0, bhh0, h0s, ga, rb, gblk);
        __syncthreads();

        // P2: layer-0 gates -> h0 (in place, per-element)
        {
            int r = tid >> 4; int jb = (tid & 15) * 8;
            const float* gi_tab = (t == 0) ? T0 : (T1 + acts[r]*G3);
            for (int j = jb; j < jb + 8; ++j) {
                float ir  = gi_tab[j];        float hr = ga[r*GA_LD + j];
                float iz  = gi_tab[128 + j];  float hz = ga[r*GA_LD + 128 + j];
                float inn = gi_tab[256 + j];  float hn = ga[r*GA_LD + 256 + j];
                float rg = sigf(ir + hr);
                float zg = sigf(iz + hz);
                float ng = tanh_fast(inn + rg*hn);
                float h  = h0s[j*H_LD + r];
                h0s[j*H_LD + r] = (1.0f - zg)*ng + zg*h;
            }
        }
        __syncthreads();

        // P3: gb = gi1 = h0' . Wih1^T + bih1 ;  P4: ga = gh1 = h1 . Whh1^T + bhh1
        gemm_phase(wih1, bih1, h0s, gb, rb, gblk);
        gemm_phase(whh1, bhh1, h1s, ga, rb, gblk);
        __syncthreads();

        // P5: layer-1 gates -> h1 (in place)
        {
            int r = tid >> 4; int jb = (tid & 15) * 8;
            for (int j = jb; j < jb + 8; ++j) {
                float ir  = gb[r*GA_LD + j];        float hr = ga[r*GA_LD + j];
                float iz  = gb[r*GA_LD + 128 + j];  float hz = ga[r*GA_LD + 128 + j];
                float inn = gb[r*GA_LD + 256 + j];  float hn = ga[r*GA_LD + 256 + j];
                float rg = sigf(ir + hr);
                float zg = sigf(iz + hz);
                float ng = tanh_fast(inn + rg*hn);
                float h  = h1s[j*H_LD + r];
                h1s[j*H_LD + r] = (1.0f - zg)*ng + zg*h;
            }
        }
        __syncthreads();

        // P6: preds = h1' . fc_w^T + fc_b  (33 outputs per row)
        {
            int r = tid & 31;
            for (int o = tid >> 5; o < NOUT; o += 16) {
                const float* w = fcw + o*HDIM;
                float acc = fcb[o];
                for (int k = 0; k < HDIM; ++k) acc += h1s[k*H_LD + r] * w[k];
                preds[r*PRED_LD + o] = acc;
            }
        }
        __syncthreads();

        // P7: per-row softmax/log_softmax over ch 0..31, argmax (first-index), store
        {
            int r = tid >> 4; int l16 = tid & 15; int c0 = l16 * 2;
            float v0 = preds[r*PRED_LD + c0];
            float v1 = preds[r*PRED_LD + c0 + 1];
            float bv; int bi;
            if (v0 >= v1) { bv = v0; bi = c0; } else { bv = v1; bi = c0 + 1; }
#pragma unroll
            for (int d = 1; d < 16; d <<= 1) {
                float ov = __shfl_xor(bv, d);
                int   oi = __shfl_xor(bi, d);
                if (ov > bv || (ov == bv && oi < bi)) { bv = ov; bi = oi; }
            }
            // bv = row max, bi = first argmax
            float e0 = __expf(v0 - bv), e1 = __expf(v1 - bv);
            float s = e0 + e1;
#pragma unroll
            for (int d = 1; d < 16; d <<= 1) s += __shfl_xor(s, d);
            float ls = __logf(s);
            float inv = 1.0f / s;
            size_t base = ((size_t)(row0 + r)*NSTEP + t)*NOUT;
            lp[base + c0]     = v0 - bv - ls;
            lp[base + c0 + 1] = v1 - bv - ls;
            pp[base + c0]     = e0 * inv;
            pp[base + c0 + 1] = e1 * inv;
            if (l16 == 0) {
                acts[r] = bi;
                lp[base + 32] = preds[r*PRED_LD + 32];  // stash raw duration logit
            }
        }
        __syncthreads();
    }
}

// Duration softmax over time (axis=1); reads raw logits stashed in lp ch32,
// overwrites ch32 of both outputs with softmax-over-t values.
__global__ void dur_kernel(float* __restrict__ out) {
    int wid  = threadIdx.x >> 6;
    int lane = threadIdx.x & 63;
    int row  = blockIdx.x * 4 + wid;
    float* lp = out;
    float* pp = out + LOGP_ELEMS;
    size_t base = (size_t)row * NSTEP * NOUT + 32;

    float v[4]; float m = -1e30f;
#pragma unroll
    for (int i = 0; i < 4; ++i) {
        v[i] = lp[base + (size_t)(lane*4 + i)*NOUT];
        m = fmaxf(m, v[i]);
    }
#pragma unroll
    for (int d = 1; d < 64; d <<= 1) m = fmaxf(m, __shfl_xor(m, d));
    float e[4]; float s = 0.0f;
#pragma unroll
    for (int i = 0; i < 4; ++i) { e[i] = __expf(v[i] - m); s += e[i]; }
#pragma unroll
    for (int d = 1; d < 64; d <<= 1) s += __shfl_xor(s, d);
    float inv = 1.0f / s;
#pragma unroll
    for (int i = 0; i < 4; ++i) {
        size_t idx = base + (size_t)(lane*4 + i)*NOUT;
        float dv = e[i] * inv;
        lp[idx] = dv;
        pp[idx] = dv;
    }
}

extern "C" void kernel_launch(void* const* d_in, const int* in_sizes, int n_in,
                              void* d_out, int out_size, void* d_ws, size_t ws_size,
                              hipStream_t stream) {
    const float* hid  = (const float*)d_in[1];
    const float* emb  = (const float*)d_in[2];
    const float* wih0 = (const float*)d_in[3];
    const float* whh0 = (const float*)d_in[4];
    const float* bih0 = (const float*)d_in[5];
    const float* bhh0 = (const float*)d_in[6];
    const float* wih1 = (const float*)d_in[7];
    const float* whh1 = (const float*)d_in[8];
    const float* bih1 = (const float*)d_in[9];
    const float* bhh1 = (const float*)d_in[10];
    const float* fcw  = (const float*)d_in[11];
    const float* fcb  = (const float*)d_in[12];

    float* T1 = (float*)d_ws;          // 32*384 floats
    float* T0 = T1 + 32*G3;            // 384 floats

    prep_kernel<<<32, 384, 0, stream>>>(emb, wih0, bih0, T1, T0);

    hipFuncSetAttribute((const void*)decoder_kernel,
                        hipFuncAttributeMaxDynamicSharedMemorySize, LDS_BYTES);
    decoder_kernel<<<BROWS/RPB, NTHR, LDS_BYTES, stream>>>(
        hid, T1, T0, whh0, bhh0, wih1, bih1, whh1, bhh1, fcw, fcb, (float*)d_out);

    dur_kernel<<<BROWS/4, 256, 0, stream>>>((float*)d_out);
}

// Round 2
// 12583.479 us; speedup vs baseline: 1.2760x; 1.2760x over previous
//
#include <hip/hip_runtime.h>

#define HDIM  128
#define G3    384
#define RPB   32
#define NTHR  512
#define NSTEP 256
#define NOUT  33
#define BROWS 8192
#define LOGP_ELEMS 69206016LL   // 8192*256*33

typedef __bf16 bf16x8 __attribute__((ext_vector_type(8)));
typedef float  f32x4  __attribute__((ext_vector_type(4)));
typedef unsigned short u16x8 __attribute__((ext_vector_type(8)));

// ---------------- LDS layout ----------------
#define H_LD    36
#define GA_LD   385
#define GN_LD   129
#define PRED_LD 34
#define OFF_H0F  0
#define OFF_H1F  (128*H_LD)                    // 4608
#define OFF_GA   (2*128*H_LD)                  // 9216
#define OFF_GN   (OFF_GA + RPB*GA_LD)          // 21536
#define OFF_PRED (OFF_GN + RPB*GN_LD)          // 25664
#define OFF_ACTS (OFF_PRED + RPB*PRED_LD)      // 26752
#define SPLIT_BASE ((OFF_ACTS + 32)*4)         // 107136 bytes, 16B aligned
#define SPLIT_LAYER_BYTES 24576                // 3 splits * 32*128*2B
#define SPLIT_S_BYTES 8192
#define LDS_BYTES (SPLIT_BASE + 2*SPLIT_LAYER_BYTES)  // 156288 < 163840

// ws layout: Bpack | T1 | T0
#define BP_BYTES (3*24*4*3*1024)               // 294912
#define NTILES   24

__device__ __forceinline__ float sigf(float x) { return 1.0f / (1.0f + __expf(-x)); }
__device__ __forceinline__ float tanh_fast(float x) { return 1.0f - 2.0f / (__expf(2.0f*x) + 1.0f); }

__device__ __forceinline__ unsigned short f2bf(float x) {
    unsigned u = __builtin_bit_cast(unsigned, x);
    unsigned r = 0x7FFFu + ((u >> 16) & 1u);
    return (unsigned short)((u + r) >> 16);
}
__device__ __forceinline__ float bf2f(unsigned short h) {
    return __builtin_bit_cast(float, ((unsigned)h) << 16);
}

// ---------------- prep: gi0 tables ----------------
__global__ void prep_kernel(const float* __restrict__ emb, const float* __restrict__ wih0,
                            const float* __restrict__ bih0, float* __restrict__ T1,
                            float* __restrict__ T0) {
    int a = blockIdx.x;          // 0..31
    int g = threadIdx.x;         // 0..383
    const float* e = emb + a * 127;
    const float* w = wih0 + g * HDIM;
    float s = bih0[g];
    for (int k = 0; k < 127; ++k) s += e[k] * w[k];
    T1[a * G3 + g] = s + w[127];
    if (a == 0) T0[g] = s;
}

// ---------------- prep: split + pack weights into B-fragments ----------------
// Bp[(((mat*24+nt)*4+kc)*3+s)*64 + lane][8 bf16]
//   element: g = nt*16 + (lane&15), k = kc*32 + (lane>>4)*8 + e, value = split_s(W[g][k])
__global__ void prep_pack(const float* __restrict__ whh0, const float* __restrict__ wih1,
                          const float* __restrict__ whh1, u16x8* __restrict__ Bp) {
    int mat = blockIdx.x / NTILES;
    int nt  = blockIdx.x % NTILES;
    const float* W = (mat == 0) ? whh0 : (mat == 1) ? wih1 : whh1;
    int tid  = threadIdx.x;        // 256
    int lane = tid & 63;
    int kc   = tid >> 6;
    int g = nt * 16 + (lane & 15);
    int k = kc * 32 + (lane >> 4) * 8;
    u16x8 v1, v2, v3;
#pragma unroll
    for (int e = 0; e < 8; ++e) {
        float x = W[g * HDIM + k + e];
        unsigned short b1 = f2bf(x);  float r1 = x - bf2f(b1);
        unsigned short b2 = f2bf(r1); float r2 = r1 - bf2f(b2);
        unsigned short b3 = f2bf(r2);
        v1[e] = b1; v2[e] = b2; v3[e] = b3;
    }
    size_t base = (size_t)(((mat * NTILES + nt) * 4 + kc) * 3) * 64 + lane;
    Bp[base]       = v1;
    Bp[base + 64]  = v2;
    Bp[base + 128] = v3;
}

// ---------------- main decoder ----------------
__launch_bounds__(NTHR)
__global__ void decoder_kernel(const float* __restrict__ hid,
                               const float* __restrict__ T1, const float* __restrict__ T0,
                               const bf16x8* __restrict__ Bp,
                               const float* __restrict__ bhh0,
                               const float* __restrict__ bih1, const float* __restrict__ bhh1,
                               const float* __restrict__ fcw,  const float* __restrict__ fcb,
                               float* __restrict__ out) {
    extern __shared__ char smraw[];
    float* sm    = (float*)smraw;
    float* h0f   = sm + OFF_H0F;    // [128][36] fp32 transposed
    float* h1f   = sm + OFF_H1F;
    float* ga    = sm + OFF_GA;     // [32][385]
    float* gn    = sm + OFF_GN;     // [32][129]
    float* preds = sm + OFF_PRED;   // [32][34]
    int*   acts  = (int*)(sm + OFF_ACTS);
    char*  h0sb  = smraw + SPLIT_BASE;                       // layer-0 splits
    char*  h1sb  = smraw + SPLIT_BASE + SPLIT_LAYER_BYTES;   // layer-1 splits

    const int tid  = threadIdx.x;
    const int row0 = blockIdx.x * RPB;
    float* lp = out;
    float* pp = out + LOGP_ELEMS;

    const int lane  = tid & 63;
    const int w     = tid >> 6;      // wave 0..7
    const int col   = lane & 15;
    const int q     = lane >> 4;
    const int akoff = q * 16;        // A-frag k byte offset within 64B chunk
    const int drow  = q * 4;         // D row base
    const int gcol  = w * 16 + col;  // gate col within a 128-gate type block

    // hoisted biases (per-lane constant)
    float bR0 = bhh0[gcol], bZ0 = bhh0[128 + gcol], bN0 = bhh0[256 + gcol];
    float iR1 = bih1[gcol], iZ1 = bih1[128 + gcol], iN1 = bih1[256 + gcol];
    float hR1 = bhh1[gcol], hZ1 = bhh1[128 + gcol], hN1 = bhh1[256 + gcol];

    // gate-phase mapping (identical to round-1 kernel)
    const int gr  = tid >> 4;          // row 0..31
    const int jb  = (tid & 15) * 8;    // 8 consecutive hidden indices
    const int spl_off = ((gr * 256 + jb * 2) ^ ((gr & 7) << 4)); // 16B-aligned

    // ---- init: h -> fp32 LDS + bf16 splits ----
    {
        int r = gr;
        const float* src0 = hid + (size_t)(row0 + r) * HDIM + jb;
        const float* src1 = src0 + (size_t)BROWS * HDIM;
        float v0[8], v1[8];
#pragma unroll
        for (int e = 0; e < 8; ++e) { v0[e] = src0[e]; v1[e] = src1[e]; }
        u16x8 a1, a2, a3, c1, c2, c3;
#pragma unroll
        for (int e = 0; e < 8; ++e) {
            h0f[(jb + e) * H_LD + r] = v0[e];
            h1f[(jb + e) * H_LD + r] = v1[e];
            unsigned short b1 = f2bf(v0[e]); float r1 = v0[e] - bf2f(b1);
            unsigned short b2 = f2bf(r1);    float r2 = r1 - bf2f(b2);
            a1[e] = b1; a2[e] = b2; a3[e] = f2bf(r2);
            b1 = f2bf(v1[e]); r1 = v1[e] - bf2f(b1);
            b2 = f2bf(r1);    r2 = r1 - bf2f(b2);
            c1[e] = b1; c2[e] = b2; c3[e] = f2bf(r2);
        }
        *(u16x8*)(h0sb + 0 * SPLIT_S_BYTES + spl_off) = a1;
        *(u16x8*)(h0sb + 1 * SPLIT_S_BYTES + spl_off) = a2;
        *(u16x8*)(h0sb + 2 * SPLIT_S_BYTES + spl_off) = a3;
        *(u16x8*)(h1sb + 0 * SPLIT_S_BYTES + spl_off) = c1;
        *(u16x8*)(h1sb + 1 * SPLIT_S_BYTES + spl_off) = c2;
        *(u16x8*)(h1sb + 2 * SPLIT_S_BYTES + spl_off) = c3;
    }
    __syncthreads();

    for (int t = 0; t < NSTEP; ++t) {
        // ---- P1: gh0 = h0 . whh0^T + bhh0  (MFMA, 6-product split) ----
        {
            f32x4 acc[3][2];
#pragma unroll
            for (int ty = 0; ty < 3; ++ty) {
                float bb = (ty == 0) ? bR0 : (ty == 1) ? bZ0 : bN0;
                f32x4 bv = {bb, bb, bb, bb};
                acc[ty][0] = bv; acc[ty][1] = bv;
            }
#pragma unroll
            for (int kc = 0; kc < 4; ++kc) {
                bf16x8 a[3][2];
#pragma unroll
                for (int s = 0; s < 3; ++s)
#pragma unroll
                    for (int Mt = 0; Mt < 2; ++Mt) {
                        int row = Mt * 16 + col;
                        int off = (row * 256 + kc * 64 + akoff) ^ ((row & 7) << 4);
                        a[s][Mt] = *(const bf16x8*)(h0sb + s * SPLIT_S_BYTES + off);
                    }
#pragma unroll
                for (int ty = 0; ty < 3; ++ty) {
                    int nt = ty * 8 + w;
                    const bf16x8* bp = Bp + (size_t)(((0 * NTILES + nt) * 4 + kc) * 3) * 64 + lane;
                    bf16x8 b1 = bp[0], b2 = bp[64], b3 = bp[128];
#pragma unroll
                    for (int Mt = 0; Mt < 2; ++Mt) {
                        acc[ty][Mt] = __builtin_amdgcn_mfma_f32_16x16x32_bf16(a[0][Mt], b1, acc[ty][Mt], 0, 0, 0);
                        acc[ty][Mt] = __builtin_amdgcn_mfma_f32_16x16x32_bf16(a[0][Mt], b2, acc[ty][Mt], 0, 0, 0);
                        acc[ty][Mt] = __builtin_amdgcn_mfma_f32_16x16x32_bf16(a[1][Mt], b1, acc[ty][Mt], 0, 0, 0);
                        acc[ty][Mt] = __builtin_amdgcn_mfma_f32_16x16x32_bf16(a[0][Mt], b3, acc[ty][Mt], 0, 0, 0);
                        acc[ty][Mt] = __builtin_amdgcn_mfma_f32_16x16x32_bf16(a[1][Mt], b2, acc[ty][Mt], 0, 0, 0);
                        acc[ty][Mt] = __builtin_amdgcn_mfma_f32_16x16x32_bf16(a[2][Mt], b1, acc[ty][Mt], 0, 0, 0);
                    }
                }
            }
#pragma unroll
            for (int ty = 0; ty < 3; ++ty)
#pragma unroll
                for (int Mt = 0; Mt < 2; ++Mt)
#pragma unroll
                    for (int i = 0; i < 4; ++i) {
                        int r = Mt * 16 + drow + i;
                        ga[r * GA_LD + ty * 128 + gcol] = acc[ty][Mt][i];
                    }
        }
        __syncthreads();

        // ---- P2: layer-0 gates -> h0 (fp32 LDS) + new bf16 splits ----
        {
            const float* gi_tab = (t == 0) ? T0 : (T1 + acts[gr] * G3);
            float hv[8];
#pragma unroll
            for (int c = 0; c < 8; ++c) {
                int j = jb + c;
                float ir  = gi_tab[j];        float hr = ga[gr * GA_LD + j];
                float iz  = gi_tab[128 + j];  float hz = ga[gr * GA_LD + 128 + j];
                float inn = gi_tab[256 + j];  float hn = ga[gr * GA_LD + 256 + j];
                float rg = sigf(ir + hr);
                float zg = sigf(iz + hz);
                float ng = tanh_fast(inn + rg * hn);
                float h  = h0f[j * H_LD + gr];
                float hnew = (1.0f - zg) * ng + zg * h;
                h0f[j * H_LD + gr] = hnew;
                hv[c] = hnew;
            }
            u16x8 s1, s2, s3;
#pragma unroll
            for (int e = 0; e < 8; ++e) {
                float x = hv[e];
                unsigned short b1 = f2bf(x);  float r1 = x - bf2f(b1);
                unsigned short b2 = f2bf(r1); float r2 = r1 - bf2f(b2);
                s1[e] = b1; s2[e] = b2; s3[e] = f2bf(r2);
            }
            *(u16x8*)(h0sb + 0 * SPLIT_S_BYTES + spl_off) = s1;
            *(u16x8*)(h0sb + 1 * SPLIT_S_BYTES + spl_off) = s2;
            *(u16x8*)(h0sb + 2 * SPLIT_S_BYTES + spl_off) = s3;
        }
        __syncthreads();

        // ---- P3/P4: gi1 (A=h0 new) and gh1 (A=h1 old), fused sums to LDS ----
        {
            f32x4 ai[3][2], ah[3][2];
#pragma unroll
            for (int ty = 0; ty < 3; ++ty) {
                float bi = (ty == 0) ? iR1 : (ty == 1) ? iZ1 : iN1;
                float bh = (ty == 0) ? hR1 : (ty == 1) ? hZ1 : hN1;
                f32x4 bvi = {bi, bi, bi, bi}, bvh = {bh, bh, bh, bh};
                ai[ty][0] = bvi; ai[ty][1] = bvi;
                ah[ty][0] = bvh; ah[ty][1] = bvh;
            }
#pragma unroll
            for (int kc = 0; kc < 4; ++kc) {
                bf16x8 a0[3][2], a1[3][2];
#pragma unroll
                for (int s = 0; s < 3; ++s)
#pragma unroll
                    for (int Mt = 0; Mt < 2; ++Mt) {
                        int row = Mt * 16 + col;
                        int off = (row * 256 + kc * 64 + akoff) ^ ((row & 7) << 4);
                        a0[s][Mt] = *(const bf16x8*)(h0sb + s * SPLIT_S_BYTES + off);
                        a1[s][Mt] = *(const bf16x8*)(h1sb + s * SPLIT_S_BYTES + off);
                    }
#pragma unroll
                for (int ty = 0; ty < 3; ++ty) {
                    int nt = ty * 8 + w;
                    const bf16x8* bpi = Bp + (size_t)(((1 * NTILES + nt) * 4 + kc) * 3) * 64 + lane;
                    const bf16x8* bph = Bp + (size_t)(((2 * NTILES + nt) * 4 + kc) * 3) * 64 + lane;
                    bf16x8 bi1 = bpi[0], bi2 = bpi[64], bi3 = bpi[128];
                    bf16x8 bh1 = bph[0], bh2 = bph[64], bh3 = bph[128];
#pragma unroll
                    for (int Mt = 0; Mt < 2; ++Mt) {
                        ai[ty][Mt] = __builtin_amdgcn_mfma_f32_16x16x32_bf16(a0[0][Mt], bi1, ai[ty][Mt], 0, 0, 0);
                        ai[ty][Mt] = __builtin_amdgcn_mfma_f32_16x16x32_bf16(a0[0][Mt], bi2, ai[ty][Mt], 0, 0, 0);
                        ai[ty][Mt] = __builtin_amdgcn_mfma_f32_16x16x32_bf16(a0[1][Mt], bi1, ai[ty][Mt], 0, 0, 0);
                        ai[ty][Mt] = __builtin_amdgcn_mfma_f32_16x16x32_bf16(a0[0][Mt], bi3, ai[ty][Mt], 0, 0, 0);
                        ai[ty][Mt] = __builtin_amdgcn_mfma_f32_16x16x32_bf16(a0[1][Mt], bi2, ai[ty][Mt], 0, 0, 0);
                        ai[ty][Mt] = __builtin_amdgcn_mfma_f32_16x16x32_bf16(a0[2][Mt], bi1, ai[ty][Mt], 0, 0, 0);
                        ah[ty][Mt] = __builtin_amdgcn_mfma_f32_16x16x32_bf16(a1[0][Mt], bh1, ah[ty][Mt], 0, 0, 0);
                        ah[ty][Mt] = __builtin_amdgcn_mfma_f32_16x16x32_bf16(a1[0][Mt], bh2, ah[ty][Mt], 0, 0, 0);
                        ah[ty][Mt] = __builtin_amdgcn_mfma_f32_16x16x32_bf16(a1[1][Mt], bh1, ah[ty][Mt], 0, 0, 0);
                        ah[ty][Mt] = __builtin_amdgcn_mfma_f32_16x16x32_bf16(a1[0][Mt], bh3, ah[ty][Mt], 0, 0, 0);
                        ah[ty][Mt] = __builtin_amdgcn_mfma_f32_16x16x32_bf16(a1[1][Mt], bh2, ah[ty][Mt], 0, 0, 0);
                        ah[ty][Mt] = __builtin_amdgcn_mfma_f32_16x16x32_bf16(a1[2][Mt], bh1, ah[ty][Mt], 0, 0, 0);
                    }
                }
            }
            // write r,z sums; n parts separate (n needs inn + r*hn)
#pragma unroll
            for (int Mt = 0; Mt < 2; ++Mt)
#pragma unroll
                for (int i = 0; i < 4; ++i) {
                    int r = Mt * 16 + drow + i;
                    ga[r * GA_LD + gcol]        = ai[0][Mt][i] + ah[0][Mt][i];
                    ga[r * GA_LD + 128 + gcol]  = ai[1][Mt][i] + ah[1][Mt][i];
                    ga[r * GA_LD + 256 + gcol]  = ai[2][Mt][i];
                    gn[r * GN_LD + gcol]        = ah[2][Mt][i];
                }
        }
        __syncthreads();

        // ---- P5: layer-1 gates -> h1 + new splits ----
        {
            float hv[8];
#pragma unroll
            for (int c = 0; c < 8; ++c) {
                int j = jb + c;
                float rs  = ga[gr * GA_LD + j];
                float zs  = ga[gr * GA_LD + 128 + j];
                float inn = ga[gr * GA_LD + 256 + j];
                float hnv = gn[gr * GN_LD + j];
                float rg = sigf(rs);
                float zg = sigf(zs);
                float ng = tanh_fast(inn + rg * hnv);
                float h  = h1f[j * H_LD + gr];
                float hnew = (1.0f - zg) * ng + zg * h;
                h1f[j * H_LD + gr] = hnew;
                hv[c] = hnew;
            }
            u16x8 s1, s2, s3;
#pragma unroll
            for (int e = 0; e < 8; ++e) {
                float x = hv[e];
                unsigned short b1 = f2bf(x);  float r1 = x - bf2f(b1);
                unsigned short b2 = f2bf(r1); float r2 = r1 - bf2f(b2);
                s1[e] = b1; s2[e] = b2; s3[e] = f2bf(r2);
            }
            *(u16x8*)(h1sb + 0 * SPLIT_S_BYTES + spl_off) = s1;
            *(u16x8*)(h1sb + 1 * SPLIT_S_BYTES + spl_off) = s2;
            *(u16x8*)(h1sb + 2 * SPLIT_S_BYTES + spl_off) = s3;
        }
        __syncthreads();

        // ---- P6: preds = h1 . fc_w^T + fc_b ----
        {
            int r = tid & 31;
            for (int o = tid >> 5; o < NOUT; o += 16) {
                const float* wv = fcw + o * HDIM;
                float acc = fcb[o];
                for (int k = 0; k < HDIM; ++k) acc += h1f[k * H_LD + r] * wv[k];
                preds[r * PRED_LD + o] = acc;
            }
        }
        __syncthreads();

        // ---- P7: softmax/log_softmax + argmax (first-index), store ----
        {
            int r = tid >> 4; int l16 = tid & 15; int c0 = l16 * 2;
            float v0 = preds[r * PRED_LD + c0];
            float v1 = preds[r * PRED_LD + c0 + 1];
            float bv; int bi;
            if (v0 >= v1) { bv = v0; bi = c0; } else { bv = v1; bi = c0 + 1; }
#pragma unroll
            for (int d = 1; d < 16; d <<= 1) {
                float ov = __shfl_xor(bv, d);
                int   oi = __shfl_xor(bi, d);
                if (ov > bv || (ov == bv && oi < bi)) { bv = ov; bi = oi; }
            }
            float e0 = __expf(v0 - bv), e1 = __expf(v1 - bv);
            float s = e0 + e1;
#pragma unroll
            for (int d = 1; d < 16; d <<= 1) s += __shfl_xor(s, d);
            float ls = __logf(s);
            float inv = 1.0f / s;
            size_t base = ((size_t)(row0 + r) * NSTEP + t) * NOUT;
            lp[base + c0]     = v0 - bv - ls;
            lp[base + c0 + 1] = v1 - bv - ls;
            pp[base + c0]     = e0 * inv;
            pp[base + c0 + 1] = e1 * inv;
            if (l16 == 0) {
                acts[r] = bi;
                lp[base + 32] = preds[r * PRED_LD + 32];  // raw duration logit stash
            }
        }
        __syncthreads();
    }
}

// ---------------- duration softmax over time ----------------
__global__ void dur_kernel(float* __restrict__ out) {
    int wid  = threadIdx.x >> 6;
    int lane = threadIdx.x & 63;
    int row  = blockIdx.x * 4 + wid;
    float* lp = out;
    float* pp = out + LOGP_ELEMS;
    size_t base = (size_t)row * NSTEP * NOUT + 32;

    float v[4]; float m = -1e30f;
#pragma unroll
    for (int i = 0; i < 4; ++i) {
        v[i] = lp[base + (size_t)(lane * 4 + i) * NOUT];
        m = fmaxf(m, v[i]);
    }
#pragma unroll
    for (int d = 1; d < 64; d <<= 1) m = fmaxf(m, __shfl_xor(m, d));
    float e[4]; float s = 0.0f;
#pragma unroll
    for (int i = 0; i < 4; ++i) { e[i] = __expf(v[i] - m); s += e[i]; }
#pragma unroll
    for (int d = 1; d < 64; d <<= 1) s += __shfl_xor(s, d);
    float inv = 1.0f / s;
#pragma unroll
    for (int i = 0; i < 4; ++i) {
        size_t idx = base + (size_t)(lane * 4 + i) * NOUT;
        float dv = e[i] * inv;
        lp[idx] = dv;
        pp[idx] = dv;
    }
}

extern "C" void kernel_launch(void* const* d_in, const int* in_sizes, int n_in,
                              void* d_out, int out_size, void* d_ws, size_t ws_size,
                              hipStream_t stream) {
    const float* hid  = (const float*)d_in[1];
    const float* emb  = (const float*)d_in[2];
    const float* wih0 = (const float*)d_in[3];
    const float* whh0 = (const float*)d_in[4];
    const float* bih0 = (const float*)d_in[5];
    const float* bhh0 = (const float*)d_in[6];
    const float* wih1 = (const float*)d_in[7];
    const float* whh1 = (const float*)d_in[8];
    const float* bih1 = (const float*)d_in[9];
    const float* bhh1 = (const float*)d_in[10];
    const float* fcw  = (const float*)d_in[11];
    const float* fcb  = (const float*)d_in[12];

    char*  ws = (char*)d_ws;
    u16x8* Bp = (u16x8*)ws;                       // 294912 B
    float* T1 = (float*)(ws + BP_BYTES);          // 32*384 f32
    float* T0 = T1 + 32 * G3;                     // 384 f32

    prep_kernel<<<32, 384, 0, stream>>>(emb, wih0, bih0, T1, T0);
    prep_pack<<<3 * NTILES, 256, 0, stream>>>(whh0, wih1, whh1, Bp);

    hipFuncSetAttribute((const void*)decoder_kernel,
                        hipFuncAttributeMaxDynamicSharedMemorySize, LDS_BYTES);
    decoder_kernel<<<BROWS / RPB, NTHR, LDS_BYTES, stream>>>(
        hid, T1, T0, (const bf16x8*)Bp, bhh0, bih1, bhh1, fcw, fcb, (float*)d_out);

    dur_kernel<<<BROWS / 4, 256, 0, stream>>>((float*)d_out);
}

// Round 3
// 5212.005 us; speedup vs baseline: 3.0807x; 2.4143x over previous
//
#include <hip/hip_runtime.h>

#define HDIM  128
#define G3    384
#define RPB   32
#define NTHR  512
#define NSTEP 256
#define NOUT  33
#define BROWS 8192
#define LOGP_ELEMS 69206016LL   // 8192*256*33

typedef _Float16 half8 __attribute__((ext_vector_type(8)));
typedef float    f32x4 __attribute__((ext_vector_type(4)));

// ---------------- LDS byte layout (total 160128 <= 163840) ----------------
#define HS0_OFF   0              // h0 splits: 2 x [32 rows][128 k] fp16, XOR-swizzled  (16384 B)
#define HS1_OFF   16384          // h1 splits                                            (16384 B)
#define BST_OFF   32768          // B stage: 8 waves x 4 ring x 3 tiles x 1024 B        (98304 B)
#define FCW_OFF   131072         // fc weights: 3 nt x 4 kc x 2 s x 1024 B              (24576 B)
#define PRED_OFF  155648         // preds [32][34] f32                                   (4352 B)
#define ACTS_OFF  160000         // acts [32] int                                        (128 B)
#define LDS_BYTES 160128
#define PRED_LD   34

// ---------------- ws layout ----------------
#define WP_BYTES  589824         // 3 mats x 24 nt x 4 kc x 2 s x 1024 B
#define FP_BYTES  24576          // fc: 3 nt x 4 kc x 2 s x 1024 B

__device__ __forceinline__ float sigf(float x) { return 1.0f / (1.0f + __expf(-x)); }
__device__ __forceinline__ float tanh_fast(float x) { return 1.0f - 2.0f / (__expf(2.0f*x) + 1.0f); }

// ---------------- prep: gi0 tables (fp32) ----------------
__global__ void prep_kernel(const float* __restrict__ emb, const float* __restrict__ wih0,
                            const float* __restrict__ bih0, float* __restrict__ T1,
                            float* __restrict__ T0) {
    int a = blockIdx.x;          // 0..31
    int g = threadIdx.x;         // 0..383
    const float* e = emb + a * 127;
    const float* w = wih0 + g * HDIM;
    float s = bih0[g];
    for (int k = 0; k < 127; ++k) s += e[k] * w[k];
    T1[a * G3 + g] = s + w[127];
    if (a == 0) T0[g] = s;
}

// ---------------- prep: fp16 2-split B-fragment packing ----------------
// Weight tiles: WP[(((mat*24+nt)*4+kc)*2+s)*1024 + lane*16] : lane holds B[g=nt*16+(lane&15)][k=kc*32+(lane>>4)*8+e]
// fc tiles   : FP[((nt*4+kc)*2+s)*1024 + ...] with g>=33 zero-padded
__global__ void prep_pack(const float* __restrict__ whh0, const float* __restrict__ wih1,
                          const float* __restrict__ whh1, const float* __restrict__ fcw,
                          half8* __restrict__ WP) {
    int b = blockIdx.x;            // 0..74 : 0-71 weights, 72-74 fc
    int tid  = threadIdx.x;        // 256
    int lane = tid & 63;
    int kc   = tid >> 6;
    int nt, g, tile_base;
    const float* W;
    bool isfc = (b >= 72);
    if (!isfc) {
        int mat = b / 24; nt = b % 24;
        W = (mat == 0) ? whh0 : (mat == 1) ? wih1 : whh1;
        g = nt * 16 + (lane & 15);
        tile_base = ((mat * 24 + nt) * 4 + kc) * 2;
    } else {
        nt = b - 72;
        W = fcw;
        g = nt * 16 + (lane & 15);
        tile_base = (WP_BYTES / 1024) + (nt * 4 + kc) * 2;
    }
    int k = kc * 32 + (lane >> 4) * 8;
    half8 v1, v2;
#pragma unroll
    for (int e = 0; e < 8; ++e) {
        float x = (isfc && g >= NOUT) ? 0.0f : W[g * HDIM + k + e];
        _Float16 s1 = (_Float16)x;
        _Float16 s2 = (_Float16)(x - (float)s1);
        v1[e] = s1; v2[e] = s2;
    }
    WP[(size_t)tile_base * 64 + lane]      = v1;
    WP[(size_t)(tile_base + 1) * 64 + lane] = v2;
}

// ---------------- main decoder ----------------
__launch_bounds__(NTHR, 2)
__global__ void decoder_kernel(const float* __restrict__ hid,
                               const float* __restrict__ T1, const float* __restrict__ T0,
                               const char* __restrict__ Bpg,
                               const float* __restrict__ bhh0,
                               const float* __restrict__ bih1, const float* __restrict__ bhh1,
                               const float* __restrict__ fcb,
                               float* __restrict__ out) {
    extern __shared__ char smraw[];
    char*  hs0   = smraw + HS0_OFF;
    char*  hs1   = smraw + HS1_OFF;
    char*  bst   = smraw + BST_OFF;
    char*  fcl   = smraw + FCW_OFF;
    float* preds = (float*)(smraw + PRED_OFF);
    int*   acts  = (int*)(smraw + ACTS_OFF);

    const int tid  = threadIdx.x;
    const int row0 = blockIdx.x * RPB;
    float* lp = out;
    float* pp = out + LOGP_ELEMS;

    const int lane = tid & 63;
    const int w    = tid >> 6;       // wave 0..7
    const int col  = lane & 15;
    const int q    = lane >> 4;
    const int akoff = q * 16;        // A-frag byte offset within 64B k-chunk
    const int j    = w * 16 + col;   // hidden/gate column owned by this lane

    // per-lane biases for gate accumulators
    const float bR0 = bhh0[j], bZ0 = bhh0[128 + j], bN0 = bhh0[256 + j];
    const float iR1 = bih1[j], iZ1 = bih1[128 + j], iN1 = bih1[256 + j];
    const float hR1 = bhh1[j], hZ1 = bhh1[128 + j], hN1 = bhh1[256 + j];

    // fc assignment (waves 0..5)
    const int fnt = w >> 1, fMt = w & 1;
    const int fo  = fnt * 16 + col;
    const float fbias = (w < 6 && fo < NOUT) ? fcb[fo] : 0.0f;

    // ---- init: stage fc weights to LDS ----
    {
        const uint4* src = (const uint4*)(Bpg + WP_BYTES);
        uint4* dst = (uint4*)fcl;
        for (int i = tid; i < FP_BYTES / 16; i += NTHR) dst[i] = src[i];
    }

    // ---- init: h0/h1 -> VGPRs + fp16 splits to LDS ----
    float h0v[2][4], h1v[2][4];
#pragma unroll
    for (int Mt = 0; Mt < 2; ++Mt)
#pragma unroll
        for (int i = 0; i < 4; ++i) {
            int row = Mt * 16 + q * 4 + i;
            float v0 = hid[(size_t)(row0 + row) * HDIM + j];
            float v1 = hid[(size_t)BROWS * HDIM + (size_t)(row0 + row) * HDIM + j];
            h0v[Mt][i] = v0; h1v[Mt][i] = v1;
            int off = (row * 256 + j * 2) ^ ((row & 7) << 4);
            _Float16 a1 = (_Float16)v0; _Float16 a2 = (_Float16)(v0 - (float)a1);
            *(_Float16*)(hs0 + off) = a1;
            *(_Float16*)(hs0 + 8192 + off) = a2;
            a1 = (_Float16)v1; a2 = (_Float16)(v1 - (float)a1);
            *(_Float16*)(hs1 + off) = a1;
            *(_Float16*)(hs1 + 8192 + off) = a2;
        }
    __syncthreads();

    // ---- staging helper state ----
    // chunk id G: c = G%24, mat = c/8, kc = (c%8)>>1, s = c&1, ring r = G&3
    // per-wave buffer: bst + ((w*4 + r)*3 + ty)*1024
    char* const mybuf = bst + (size_t)w * 4 * 3072;

#define STAGE(G)  do {                                                          \
        int c_   = (G) % 24;                                                    \
        int mat_ = c_ >> 3;                                                     \
        int kc_  = (c_ & 7) >> 1;                                               \
        int s_   = c_ & 1;                                                      \
        char* dst_ = mybuf + (size_t)((G) & 3) * 3072;                          \
        _Pragma("unroll")                                                       \
        for (int ty_ = 0; ty_ < 3; ++ty_) {                                     \
            int nt_ = ty_ * 8 + w;                                              \
            const char* src_ = Bpg + (size_t)((((mat_ * 24 + nt_) * 4 + kc_) * 2 + s_) * 1024) + lane * 16; \
            __builtin_amdgcn_global_load_lds((const unsigned int*)src_,         \
                                             (unsigned int*)(dst_ + ty_ * 1024), 16, 0, 0); \
        }                                                                       \
    } while (0)

#define VMW()  asm volatile("s_waitcnt vmcnt(9)" ::: "memory")
#define LGKM0() asm volatile("s_waitcnt lgkmcnt(0)" ::: "memory")
#define BAR()  __builtin_amdgcn_s_barrier()

    // prologue: stage chunks 0,1,2
    STAGE(0); STAGE(1); STAGE(2);

    for (int t = 0; t < NSTEP; ++t) {
        const int G0 = t * 24;

        // ================= P1: gh0 = h0_old . whh0^T + bhh0 =================
        f32x4 g0[3][2];
#pragma unroll
        for (int ty = 0; ty < 3; ++ty) {
            float bb = (ty == 0) ? bR0 : (ty == 1) ? bZ0 : bN0;
            f32x4 bv = {bb, bb, bb, bb};
            g0[ty][0] = bv; g0[ty][1] = bv;
        }
        {
            half8 a1[2], a2[2];
#pragma unroll
            for (int c = 0; c < 8; ++c) {
                STAGE(G0 + c + 3);
                VMW();
                int kc = c >> 1, s = c & 1;
                if (s == 0) {
#pragma unroll
                    for (int Mt = 0; Mt < 2; ++Mt) {
                        int row = Mt * 16 + col;
                        int off = (row * 256 + kc * 64 + akoff) ^ ((row & 7) << 4);
                        a1[Mt] = *(const half8*)(hs0 + off);
                        a2[Mt] = *(const half8*)(hs0 + 8192 + off);
                    }
                }
                char* buf = mybuf + (size_t)((G0 + c) & 3) * 3072;
#pragma unroll
                for (int ty = 0; ty < 3; ++ty) {
                    half8 b = *(const half8*)(buf + ty * 1024 + lane * 16);
#pragma unroll
                    for (int Mt = 0; Mt < 2; ++Mt) {
                        g0[ty][Mt] = __builtin_amdgcn_mfma_f32_16x16x32_f16(a1[Mt], b, g0[ty][Mt], 0, 0, 0);
                        if (s == 0)
                            g0[ty][Mt] = __builtin_amdgcn_mfma_f32_16x16x32_f16(a2[Mt], b, g0[ty][Mt], 0, 0, 0);
                    }
                }
            }
        }
        LGKM0(); BAR();   // P1 reads of hs0 done before P2 rewrites it

        // ================= P2: layer-0 gates (in-lane) =================
        {
#pragma unroll
            for (int Mt = 0; Mt < 2; ++Mt)
#pragma unroll
                for (int i = 0; i < 4; ++i) {
                    int row = Mt * 16 + q * 4 + i;
                    const float* tab;
                    if (t == 0) tab = T0;
                    else        tab = T1 + acts[row] * G3;
                    float ir  = tab[j];
                    float iz  = tab[128 + j];
                    float inn = tab[256 + j];
                    float rg = sigf(ir + g0[0][Mt][i]);
                    float zg = sigf(iz + g0[1][Mt][i]);
                    float ng = tanh_fast(inn + rg * g0[2][Mt][i]);
                    float hnew = (1.0f - zg) * ng + zg * h0v[Mt][i];
                    h0v[Mt][i] = hnew;
                    int off = (row * 256 + j * 2) ^ ((row & 7) << 4);
                    _Float16 s1 = (_Float16)hnew;
                    _Float16 s2 = (_Float16)(hnew - (float)s1);
                    *(_Float16*)(hs0 + off) = s1;
                    *(_Float16*)(hs0 + 8192 + off) = s2;
                }
        }
        LGKM0(); BAR();   // hs0 new visible

        // ================= P3: gi1 = h0_new . wih1^T + bih1 =================
        f32x4 ai[3][2], ah[3][2];
#pragma unroll
        for (int ty = 0; ty < 3; ++ty) {
            float bi = (ty == 0) ? iR1 : (ty == 1) ? iZ1 : iN1;
            float bh = (ty == 0) ? hR1 : (ty == 1) ? hZ1 : hN1;
            f32x4 bvi = {bi, bi, bi, bi}, bvh = {bh, bh, bh, bh};
            ai[ty][0] = bvi; ai[ty][1] = bvi;
            ah[ty][0] = bvh; ah[ty][1] = bvh;
        }
        {
            half8 a1[2], a2[2];
#pragma unroll
            for (int c = 8; c < 16; ++c) {
                STAGE(G0 + c + 3);
                VMW();
                int kc = (c & 7) >> 1, s = c & 1;
                if (s == 0) {
#pragma unroll
                    for (int Mt = 0; Mt < 2; ++Mt) {
                        int row = Mt * 16 + col;
                        int off = (row * 256 + kc * 64 + akoff) ^ ((row & 7) << 4);
                        a1[Mt] = *(const half8*)(hs0 + off);
                        a2[Mt] = *(const half8*)(hs0 + 8192 + off);
                    }
                }
                char* buf = mybuf + (size_t)((G0 + c) & 3) * 3072;
#pragma unroll
                for (int ty = 0; ty < 3; ++ty) {
                    half8 b = *(const half8*)(buf + ty * 1024 + lane * 16);
#pragma unroll
                    for (int Mt = 0; Mt < 2; ++Mt) {
                        ai[ty][Mt] = __builtin_amdgcn_mfma_f32_16x16x32_f16(a1[Mt], b, ai[ty][Mt], 0, 0, 0);
                        if (s == 0)
                            ai[ty][Mt] = __builtin_amdgcn_mfma_f32_16x16x32_f16(a2[Mt], b, ai[ty][Mt], 0, 0, 0);
                    }
                }
            }
        }
        // ================= P4: gh1 = h1_old . whh1^T + bhh1 =================
        {
            half8 a1[2], a2[2];
#pragma unroll
            for (int c = 16; c < 24; ++c) {
                STAGE(G0 + c + 3);       // wraps into next step's chunks
                VMW();
                int kc = (c & 7) >> 1, s = c & 1;
                if (s == 0) {
#pragma unroll
                    for (int Mt = 0; Mt < 2; ++Mt) {
                        int row = Mt * 16 + col;
                        int off = (row * 256 + kc * 64 + akoff) ^ ((row & 7) << 4);
                        a1[Mt] = *(const half8*)(hs1 + off);
                        a2[Mt] = *(const half8*)(hs1 + 8192 + off);
                    }
                }
                char* buf = mybuf + (size_t)((G0 + c) & 3) * 3072;
#pragma unroll
                for (int ty = 0; ty < 3; ++ty) {
                    half8 b = *(const half8*)(buf + ty * 1024 + lane * 16);
#pragma unroll
                    for (int Mt = 0; Mt < 2; ++Mt) {
                        ah[ty][Mt] = __builtin_amdgcn_mfma_f32_16x16x32_f16(a1[Mt], b, ah[ty][Mt], 0, 0, 0);
                        if (s == 0)
                            ah[ty][Mt] = __builtin_amdgcn_mfma_f32_16x16x32_f16(a2[Mt], b, ah[ty][Mt], 0, 0, 0);
                    }
                }
            }
        }
        LGKM0(); BAR();   // P4 reads of hs1 done before P5 rewrites it

        // ================= P5: layer-1 gates (in-lane) =================
        {
#pragma unroll
            for (int Mt = 0; Mt < 2; ++Mt)
#pragma unroll
                for (int i = 0; i < 4; ++i) {
                    int row = Mt * 16 + q * 4 + i;
                    float rg = sigf(ai[0][Mt][i] + ah[0][Mt][i]);
                    float zg = sigf(ai[1][Mt][i] + ah[1][Mt][i]);
                    float ng = tanh_fast(ai[2][Mt][i] + rg * ah[2][Mt][i]);
                    float hnew = (1.0f - zg) * ng + zg * h1v[Mt][i];
                    h1v[Mt][i] = hnew;
                    int off = (row * 256 + j * 2) ^ ((row & 7) << 4);
                    _Float16 s1 = (_Float16)hnew;
                    _Float16 s2 = (_Float16)(hnew - (float)s1);
                    *(_Float16*)(hs1 + off) = s1;
                    *(_Float16*)(hs1 + 8192 + off) = s2;
                }
        }
        LGKM0(); BAR();   // hs1 new visible

        // ================= P6: preds = h1_new . fc_w^T + fc_b (MFMA, waves 0-5) =================
        if (w < 6) {
            f32x4 acc = {fbias, fbias, fbias, fbias};
            half8 a1, a2;
#pragma unroll
            for (int kc = 0; kc < 4; ++kc) {
                int row = fMt * 16 + col;
                int off = (row * 256 + kc * 64 + akoff) ^ ((row & 7) << 4);
                a1 = *(const half8*)(hs1 + off);
                a2 = *(const half8*)(hs1 + 8192 + off);
                half8 b1 = *(const half8*)(fcl + ((fnt * 4 + kc) * 2 + 0) * 1024 + lane * 16);
                half8 b2 = *(const half8*)(fcl + ((fnt * 4 + kc) * 2 + 1) * 1024 + lane * 16);
                acc = __builtin_amdgcn_mfma_f32_16x16x32_f16(a1, b1, acc, 0, 0, 0);
                acc = __builtin_amdgcn_mfma_f32_16x16x32_f16(a2, b1, acc, 0, 0, 0);
                acc = __builtin_amdgcn_mfma_f32_16x16x32_f16(a1, b2, acc, 0, 0, 0);
            }
            if (fo < NOUT) {
#pragma unroll
                for (int i = 0; i < 4; ++i) {
                    int row = fMt * 16 + q * 4 + i;
                    preds[row * PRED_LD + fo] = acc[i];
                }
            }
        }
        LGKM0(); BAR();

        // ================= P7: softmax/log_softmax + argmax + store =================
        {
            int r = tid >> 4; int l16 = tid & 15; int c0 = l16 * 2;
            float v0 = preds[r * PRED_LD + c0];
            float v1 = preds[r * PRED_LD + c0 + 1];
            float bv; int bi;
            if (v0 >= v1) { bv = v0; bi = c0; } else { bv = v1; bi = c0 + 1; }
#pragma unroll
            for (int d = 1; d < 16; d <<= 1) {
                float ov = __shfl_xor(bv, d);
                int   oi = __shfl_xor(bi, d);
                if (ov > bv || (ov == bv && oi < bi)) { bv = ov; bi = oi; }
            }
            float e0 = __expf(v0 - bv), e1 = __expf(v1 - bv);
            float s = e0 + e1;
#pragma unroll
            for (int d = 1; d < 16; d <<= 1) s += __shfl_xor(s, d);
            float ls = __logf(s);
            float inv = 1.0f / s;
            size_t base = ((size_t)(row0 + r) * NSTEP + t) * NOUT;
            lp[base + c0]     = v0 - bv - ls;
            lp[base + c0 + 1] = v1 - bv - ls;
            pp[base + c0]     = e0 * inv;
            pp[base + c0 + 1] = e1 * inv;
            if (l16 == 0) {
                acts[r] = bi;
                lp[base + 32] = preds[r * PRED_LD + 32];  // raw duration logit stash
            }
        }
        LGKM0(); BAR();
    }
#undef STAGE
#undef VMW
#undef LGKM0
#undef BAR
}

// ---------------- duration softmax over time ----------------
__global__ void dur_kernel(float* __restrict__ out) {
    int wid  = threadIdx.x >> 6;
    int lane = threadIdx.x & 63;
    int row  = blockIdx.x * 4 + wid;
    float* lp = out;
    float* pp = out + LOGP_ELEMS;
    size_t base = (size_t)row * NSTEP * NOUT + 32;

    float v[4]; float m = -1e30f;
#pragma unroll
    for (int i = 0; i < 4; ++i) {
        v[i] = lp[base + (size_t)(lane * 4 + i) * NOUT];
        m = fmaxf(m, v[i]);
    }
#pragma unroll
    for (int d = 1; d < 64; d <<= 1) m = fmaxf(m, __shfl_xor(m, d));
    float e[4]; float s = 0.0f;
#pragma unroll
    for (int i = 0; i < 4; ++i) { e[i] = __expf(v[i] - m); s += e[i]; }
#pragma unroll
    for (int d = 1; d < 64; d <<= 1) s += __shfl_xor(s, d);
    float inv = 1.0f / s;
#pragma unroll
    for (int i = 0; i < 4; ++i) {
        size_t idx = base + (size_t)(lane * 4 + i) * NOUT;
        float dv = e[i] * inv;
        lp[idx] = dv;
        pp[idx] = dv;
    }
}

extern "C" void kernel_launch(void* const* d_in, const int* in_sizes, int n_in,
                              void* d_out, int out_size, void* d_ws, size_t ws_size,
                              hipStream_t stream) {
    const float* hid  = (const float*)d_in[1];
    const float* emb  = (const float*)d_in[2];
    const float* wih0 = (const float*)d_in[3];
    const float* whh0 = (const float*)d_in[4];
    const float* bih0 = (const float*)d_in[5];
    const float* bhh0 = (const float*)d_in[6];
    const float* wih1 = (const float*)d_in[7];
    const float* whh1 = (const float*)d_in[8];
    const float* bih1 = (const float*)d_in[9];
    const float* bhh1 = (const float*)d_in[10];
    const float* fcw  = (const float*)d_in[11];
    const float* fcb  = (const float*)d_in[12];

    char*  ws = (char*)d_ws;
    half8* WP = (half8*)ws;                               // WP_BYTES + FP_BYTES
    float* T1 = (float*)(ws + WP_BYTES + FP_BYTES);       // 32*384 f32
    float* T0 = T1 + 32 * G3;                             // 384 f32

    prep_kernel<<<32, 384, 0, stream>>>(emb, wih0, bih0, T1, T0);
    prep_pack<<<75, 256, 0, stream>>>(whh0, wih1, whh1, fcw, WP);

    hipFuncSetAttribute((const void*)decoder_kernel,
                        hipFuncAttributeMaxDynamicSharedMemorySize, LDS_BYTES);
    decoder_kernel<<<BROWS / RPB, NTHR, LDS_BYTES, stream>>>(
        hid, T1, T0, ws, bhh0, bih1, bhh1, fcb, (float*)d_out);

    dur_kernel<<<BROWS / 4, 256, 0, stream>>>((float*)d_out);
}